// Round 10
// baseline (1719.191 us; speedup 1.0000x reference)
//
#include <hip/hip_runtime.h>

#define NN 2048
#define NE 32768
#define NEP 38912   // padded edge capacity: 32768 + 2048*3 (rows padded to x4)
#define DF 2048
#define TOPK 20
#define RMAXF 1e-5f
#define TCAP 64
#define DUMMY 2048

typedef __attribute__((ext_vector_type(4))) float f32x4;
typedef __attribute__((ext_vector_type(4))) unsigned short u16x4;
typedef __attribute__((ext_vector_type(8))) unsigned short u16x8;

// ---------------- zero counts/cursor; pre-fill padded cols with DUMMY ----------------
__global__ __launch_bounds__(256) void zero_kernel(int* __restrict__ counts, int* __restrict__ cursor,
                                                   unsigned short* __restrict__ cols16) {
    int idx = blockIdx.x * 256 + threadIdx.x;
    if (idx < NN) { counts[idx] = 0; cursor[idx] = 0; }
    if (idx < NEP) cols16[idx] = DUMMY;
}

// ---------------- per-row edge counts (duplicates kept) ----------------
__global__ __launch_bounds__(256) void count_kernel(const int* __restrict__ ei, int* __restrict__ counts) {
    int e = blockIdx.x * 256 + threadIdx.x;
    if (e < NE) atomicAdd(&counts[ei[e]], 1);
}

// ---------------- exclusive scan of PADDED counts -> rowptrP; winv05 = 0.5/deg ----------------
__global__ __launch_bounds__(256) void scan_kernel(const int* __restrict__ counts, int* __restrict__ rowptrP,
                                                   float* __restrict__ winv05) {
    __shared__ int part[256];
    int tid = threadIdx.x;
    int base = tid * 8;
    int loc[8];
    int s = 0;
#pragma unroll
    for (int l = 0; l < 8; ++l) {
        loc[l] = s;
        int c = counts[base + l];
        s += (c + 3) & ~3;  // pad each row to multiple of 4
    }
    part[tid] = s;
    __syncthreads();
    for (int off = 1; off < 256; off <<= 1) {
        int v = (tid >= off) ? part[tid - off] : 0;
        __syncthreads();
        part[tid] += v;
        __syncthreads();
    }
    int excl = part[tid] - s;
#pragma unroll
    for (int l = 0; l < 8; ++l) {
        rowptrP[base + l] = excl + loc[l];
        int c = counts[base + l];
        winv05[base + l] = c ? 0.5f / (float)c : 0.0f;
    }
    if (tid == 255) rowptrP[NN] = excl + s;
}

// ---------------- fill real edges into padded slots (tails stay DUMMY) ----------------
__global__ __launch_bounds__(256) void fill_kernel(const int* __restrict__ ei, const int* __restrict__ rowptrP,
                                                   int* __restrict__ cursor, unsigned short* __restrict__ cols16) {
    int e = blockIdx.x * 256 + threadIdx.x;
    if (e < NE) {
        int r = ei[e];
        int c = ei[NE + e];
        int pos = atomicAdd(&cursor[r], 1);
        cols16[rowptrP[r] + pos] = (unsigned short)c;
    }
}

// ---------------- wave-per-row push + top-20: NO barriers in the round loop ----------------
// Wave w of each block owns row = blockIdx.x*4 + w. Lane owns entries [lane*32, lane*32+32)
// of that row's R/P (registers). Per round: pushers walk their own padded edge lists
// (software-pipelined ushort4 groups) scattering amt into the wave-private D row via LDS
// atomics; DS ops of a wave complete in program order, so the gather that follows needs
// no barrier. Convergence: wave-level __any; rounds capped at TCAP (>= true ~29).
__global__ __launch_bounds__(256, 1) void push_topk_kernel(const unsigned short* __restrict__ gcols,
                                                           const int* __restrict__ rowptrP_g,
                                                           const float* __restrict__ gwinv,
                                                           float* __restrict__ tkv, int* __restrict__ tki) {
    __shared__ __align__(16) unsigned short lcols[NEP];  // 77824 B, shared by all 4 waves
    __shared__ __align__(16) float D[4][NN + 4];         // 32832 B, one row per wave (+dummy slot 2048)

    int tid = threadIdx.x;
    // ---- stage edges global->LDS (coalesced u16x8) and zero D ----
    const u16x8* g8 = (const u16x8*)gcols;
    for (int i = tid; i < NEP / 8; i += 256) *(u16x8*)&lcols[i * 8] = g8[i];
    float* Df = &D[0][0];
    for (int i = tid; i < 4 * (NN + 4); i += 256) Df[i] = 0.0f;

    int wvw = tid >> 6, lane = tid & 63;
    int row = blockIdx.x * 4 + wvw;
    float* Dw = &D[wvw][0];
    int ebase = lane << 5;  // first owned entry index

    // ---- per-lane register state: R, P, edge bounds, weights ----
    int rpl[33];
    float wvl[32];
#pragma unroll
    for (int i = 0; i < 8; ++i) {
        *(int4*)&rpl[i * 4] = *(const int4*)&rowptrP_g[ebase + i * 4];
        *(float4*)&wvl[i * 4] = *(const float4*)&gwinv[ebase + i * 4];
    }
    rpl[32] = rowptrP_g[ebase + 32];

    float R[32], P[32];
#pragma unroll
    for (int s = 0; s < 32; ++s) { R[s] = 0.0f; P[s] = 0.0f; }
    if ((row >> 5) == lane) R[row & 31] = 1.0f;  // R = e_row

    __syncthreads();  // the ONLY block barrier: staging visible

    for (int t = 0; t < TCAP; ++t) {
        // ---- phase A: owned pushers walk their padded edge lists (pipelined) ----
#pragma unroll
        for (int s = 0; s < 32; ++s) {
            float r = R[s];
            if (r >= RMAXF) {
                P[s] += 0.5f * r;
                R[s] = 0.0f;
                float amt = r * wvl[s];
                int p = rpl[s], e = rpl[s + 1];
                if (p < e) {
                    u16x4 cur = *(const u16x4*)&lcols[p];  // p multiple of 4 -> 8B aligned
                    for (p += 4; p < e; p += 4) {
                        u16x4 nxt = *(const u16x4*)&lcols[p];  // prefetch next group
                        atomicAdd(&Dw[cur[0]], amt);
                        atomicAdd(&Dw[cur[1]], amt);
                        atomicAdd(&Dw[cur[2]], amt);
                        atomicAdd(&Dw[cur[3]], amt);
                        cur = nxt;
                    }
                    atomicAdd(&Dw[cur[0]], amt);
                    atomicAdd(&Dw[cur[1]], amt);
                    atomicAdd(&Dw[cur[2]], amt);
                    atomicAdd(&Dw[cur[3]], amt);  // pads hit Dw[DUMMY], never read
                }
            }
        }
        // ---- phase E: gather own D slice, zero it, update R (wave-ordered DS, no barrier) ----
        bool above = false;
#pragma unroll
        for (int i = 0; i < 8; ++i) {
            f32x4 d = *(f32x4*)&Dw[ebase + i * 4];
            *(f32x4*)&Dw[ebase + i * 4] = (f32x4){0.f, 0.f, 0.f, 0.f};
#pragma unroll
            for (int u = 0; u < 4; ++u) {
                float rn = R[i * 4 + u] + d[u];
                R[i * 4 + u] = rn;
                above |= (rn >= RMAXF);
            }
        }
        if (!__any(above)) break;  // wave-uniform exit; skipped rounds are exact no-ops
    }

    // ---- top-20 straight from P registers (R8-proven shuffle selection) ----
    for (int s = 0; s < TOPK; ++s) {
        float bv = -1.0f;
        int bi = 0;
#pragma unroll
        for (int j = 0; j < 32; ++j) {
            if (P[j] > bv) { bv = P[j]; bi = ebase + j; }  // ascending j: lowest index kept
        }
#pragma unroll
        for (int off = 32; off >= 1; off >>= 1) {
            float ov = __shfl_xor(bv, off);
            int oi = __shfl_xor(bi, off);
            if (ov > bv || (ov == bv && oi < bi)) { bv = ov; bi = oi; }
        }
        if (lane == 0) {
            tkv[row * TOPK + s] = bv;  // P already carries the 0.5 factor
            tki[row * TOPK + s] = bi;
        }
        if ((bi >> 5) == lane) {
#pragma unroll
            for (int j = 0; j < 32; ++j)
                if (j == (bi & 31)) P[j] = -1.0f;  // static unroll: no dynamic reg indexing
        }
    }
}

// ---------------- out[row] = sum_v w_v * feats[idx_v] ----------------
__global__ __launch_bounds__(256) void final_kernel(const float* __restrict__ feats, const float* __restrict__ tkv,
                                                    const int* __restrict__ tki, float* __restrict__ out) {
    __shared__ float wv[TOPK];
    __shared__ int wi[TOPK];
    int row = blockIdx.x, tid = threadIdx.x;
    if (tid < TOPK) {
        wv[tid] = tkv[row * TOPK + tid];
        wi[tid] = tki[row * TOPK + tid];
    }
    __syncthreads();
    int c0 = tid * 8;
    float4 a0 = {0, 0, 0, 0}, a1 = {0, 0, 0, 0};
    for (int v = 0; v < TOPK; ++v) {
        float w = wv[v];
        int id = wi[v];
        const float4* fr = (const float4*)&feats[(size_t)id * DF + c0];
        float4 g0 = fr[0], g1 = fr[1];
        a0.x += w * g0.x; a0.y += w * g0.y; a0.z += w * g0.z; a0.w += w * g0.w;
        a1.x += w * g1.x; a1.y += w * g1.y; a1.z += w * g1.z; a1.w += w * g1.w;
    }
    float4* op = (float4*)&out[(size_t)row * DF + c0];
    op[0] = a0;
    op[1] = a1;
}

extern "C" void kernel_launch(void* const* d_in, const int* in_sizes, int n_in,
                              void* d_out, int out_size, void* d_ws, size_t ws_size,
                              hipStream_t stream) {
    const float* feats = (const float*)d_in[0];
    const int* ei = (const int*)d_in[1];
    float* out = (float*)d_out;

    // ws layout (cols16 first: 16B-aligned for u16x8 staging loads)
    unsigned short* cols16 = (unsigned short*)d_ws;  // NEP ushorts = 77824 B
    int* counts = (int*)(cols16 + NEP);              // 2048
    int* cursor = counts + NN;                       // 2048
    int* rowptrP = cursor + NN;                      // 2049 (+3 pad)
    float* winv05 = (float*)(rowptrP + NN + 3);      // 2048 (16B-aligned)
    float* tkv = winv05 + NN;
    int* tki = (int*)(tkv + NN * TOPK);

    zero_kernel<<<(NEP + 255) / 256, 256, 0, stream>>>(counts, cursor, cols16);
    count_kernel<<<(NE + 255) / 256, 256, 0, stream>>>(ei, counts);
    scan_kernel<<<1, 256, 0, stream>>>(counts, rowptrP, winv05);
    fill_kernel<<<(NE + 255) / 256, 256, 0, stream>>>(ei, rowptrP, cursor, cols16);
    push_topk_kernel<<<NN / 4, 256, 0, stream>>>(cols16, rowptrP, winv05, tkv, tki);
    final_kernel<<<NN, 256, 0, stream>>>(feats, tkv, tki, out);
}